// Round 15
// baseline (676.758 us; speedup 1.0000x reference)
//
#include <hip/hip_runtime.h>
#include <hip/hip_bf16.h>
#include <cstdint>
#include <cstddef>

// MultiScaleQuantizer: z (256,32,16,16) fp32, embed (4096,32) fp32.
// Outputs concat (fp32): f_hat (2097152), idx@pn=1..16 (87296), loss (1).
//
// r15 = r14 with the vq occupancy fix (phaseB@pn16 was 78us at 27% occupancy,
// VGPR=68 > 64 -> 4 waves/SIMD; pipe floors are ~10us):
//  - __launch_bounds__(256,8) on phaseA/phaseB -> VGPR capped at 64
//    (8 waves/SIMD budget)
//  - CAP 768->512: phaseB LDS 17.4 -> 14.8 KB
//  - NVC=32 for all scales: vchunk=128 = ONE staging window per block
//    (halves barriers), pn16 grid 4096->8192 blocks

#define B_   256
#define V_   4096
#define NTOT 2097152   // 256*32*16*16
#define WIN  128       // codebook window staged in LDS
#define CAP  512       // candidate list capacity per block
#define ZS   65536     // zpack column stride (max N)

using bf16x8 = __attribute__((ext_vector_type(8))) short;
using f32x4  = __attribute__((ext_vector_type(4))) float;

__device__ inline short f2bf(float f) {
  __hip_bfloat16 h = __float2bfloat16(f);
  return *reinterpret_cast<short*>(&h);
}
__device__ inline unsigned encf(float f) {        // monotone fp32 -> u32
  unsigned u = __float_as_uint(f);
  return (u & 0x80000000u) ? ~u : (u | 0x80000000u);
}
__device__ inline float decf(unsigned u) {
  unsigned b = (u & 0x80000000u) ? (u ^ 0x80000000u) : ~u;
  return __uint_as_float(b);
}
__device__ inline int keyidx(unsigned long long k) {  // decode + clamp (safety)
  int i = (int)(unsigned)(k & 0xffffffffull);
  return min(max(i, 0), V_ - 1);
}

// ---- setup: f_rest=z, zpack@pn1 (col-major), ebf, se, tables, inits ----
// block = one (b,c) plane; blockIdx.x = b*32+c
__global__ __launch_bounds__(256) void setup_kernel(
    const float* __restrict__ z, const float* __restrict__ embed,
    float* __restrict__ f_rest, float* __restrict__ zpack,
    short* __restrict__ ebf, float* __restrict__ se,
    float* __restrict__ tables, float* __restrict__ loss_slots,
    unsigned long long* __restrict__ keys0, unsigned int* __restrict__ smin0)
{
  const int tid = threadIdx.x;
  const int t = blockIdx.x * 256 + tid;
  float v = z[t];
  f_rest[t] = v;

  __shared__ float sm[256];
  sm[tid] = v;
  __syncthreads();
  if (tid == 0) {
    float s = 0.f;
    for (int i = 0; i < 256; ++i) s += sm[i];   // ref's linear i,j order
    int c = blockIdx.x & 31, b = blockIdx.x >> 5;
    zpack[c * ZS + b] = s * (1.0f / 256.0f);    // column-major
  }

  if (blockIdx.x < 16) {                        // se + ebf: 16*256 codes
    int code = blockIdx.x * 256 + tid;
    float s = 0.f;
#pragma unroll
    for (int c = 0; c < 32; ++c) {
      float e = embed[(size_t)code * 32 + c];
      ebf[(size_t)code * 32 + c] = f2bf(e);
      s += e * e;                                // sequential like ref
    }
    se[code] = s;
  } else if (blockIdx.x == 16) {
    if (tid < 64) {
      int pn_i = tid >> 4;          // 0..3 -> pn = 1,2,4,8
      int o    = tid & 15;
      int pn   = 1 << pn_i;
      double scale = (double)pn / 16.0;
      double x  = (o + 0.5) * scale - 0.5;
      double x0 = floor(x);
      double tf = x - x0;
      float row[8];
#pragma unroll
      for (int h = 0; h < 8; ++h) row[h] = 0.f;
      const double A = -0.75;
#pragma unroll
      for (int off = -1; off <= 2; ++off) {
        double s = fabs(tf - (double)off);
        double cub;
        if (s <= 1.0)      cub = ((A + 2.0) * s - (A + 3.0)) * s * s + 1.0;
        else if (s < 2.0)  cub = (((s - 5.0) * s + 8.0) * s - 4.0) * A;
        else               cub = 0.0;
        int idx = (int)x0 + off;
        idx = min(max(idx, 0), pn - 1);
        row[idx] = (float)((double)row[idx] + cub);  // numpy f32 += f64
      }
#pragma unroll
      for (int h = 0; h < 8; ++h) tables[pn_i * 128 + o * 8 + h] = row[h];
    }
  } else if (blockIdx.x == 17) {
    keys0[tid] = ~0ull;                          // pn=1: N=256
    smin0[tid] = 0xFFFFFFFFu;
  } else if (blockIdx.x >= 20 && blockIdx.x < 60) {
    loss_slots[(blockIdx.x - 20) * 256 + tid] = 0.f;   // 40*256 = 10240 zeros
  }
}

// ---------------- phase A: MFMA scan -> per-point min of s=se/2-dot ----------
// block 256 = 4 waves x 64 points; grid.x = N/256, grid.y = v-chunks
__global__ __launch_bounds__(256, 8) void vq_phaseA_kernel(
    const float* __restrict__ zpack, const short* __restrict__ ebf,
    const float* __restrict__ se, unsigned int* __restrict__ smin,
    int vchunk)
{
  __shared__ __align__(16) short elds[WIN * 40]; // padded stride 80B rows
  __shared__ float selds[WIN];

  const int tid = threadIdx.x;
  const int lane = tid & 63, wave = tid >> 6;
  const int col = lane & 15, quad = lane >> 4;
  const int nw = blockIdx.x * 256 + wave * 64;
  const int vbase = blockIdx.y * vchunk;

  // A-frags: 4 frags x 16 points; lane holds A[m=col][k=quad*8+j], A = -z bf16
  // zpack col-major: channel k at zpack[k*ZS + n] -> lane-coalesced loads
  bf16x8 af[4];
#pragma unroll
  for (int f = 0; f < 4; ++f) {
    const float* zb = zpack + (nw + f * 16 + col);
#pragma unroll
    for (int j = 0; j < 8; ++j)
      af[f][j] = f2bf(-zb[(size_t)(quad * 8 + j) * ZS]);
  }
  float mn[4][4];
#pragma unroll
  for (int f = 0; f < 4; ++f)
#pragma unroll
    for (int r = 0; r < 4; ++r) mn[f][r] = 3.4e38f;

  for (int w0 = 0; w0 < vchunk; w0 += WIN) {
    __syncthreads();
    {
      // 128 rows x 2 threads; each thread stores 2 bf16x8 = full 32-short row
      int row = tid >> 1, half = tid & 1;
      const bf16x8* src = (const bf16x8*)(ebf + (size_t)(vbase + w0 + row) * 32);
      bf16x8* dst = (bf16x8*)(elds + row * 40);
      dst[half * 2]     = src[half * 2];
      dst[half * 2 + 1] = src[half * 2 + 1];
      if (tid < WIN) selds[tid] = 0.5f * se[vbase + w0 + tid];  // *0.5 exact
    }
    __syncthreads();
    for (int vv = 0; vv < WIN; vv += 16) {
      bf16x8 bf = *(const bf16x8*)(elds + (vv + col) * 40 + quad * 8);
      float sevh = selds[vv + col];
      f32x4 cin = {sevh, sevh, sevh, sevh};       // D = se/2 + (-z)*e
#pragma unroll
      for (int f = 0; f < 4; ++f) {
        f32x4 d = __builtin_amdgcn_mfma_f32_16x16x32_bf16(af[f], bf, cin, 0, 0, 0);
#pragma unroll
        for (int r = 0; r < 4; ++r) mn[f][r] = fminf(mn[f][r], d[r]);
      }
    }
  }
  // cross-col min via shuffle butterfly
#pragma unroll
  for (int f = 0; f < 4; ++f)
#pragma unroll
    for (int r = 0; r < 4; ++r) {
      float m = mn[f][r];
      m = fminf(m, __shfl_xor(m, 1, 64));
      m = fminf(m, __shfl_xor(m, 2, 64));
      m = fminf(m, __shfl_xor(m, 4, 64));
      m = fminf(m, __shfl_xor(m, 8, 64));
      mn[f][r] = m;
    }
  if (col == 0) {
#pragma unroll
    for (int f = 0; f < 4; ++f)
#pragma unroll
      for (int r = 0; r < 4; ++r)
        atomicMin(&smin[nw + f * 16 + quad * 4 + r], encf(mn[f][r]));
  }
}

// -------- phase B: MFMA re-scan; candidates -> LDS list -> batch rescue -----
__global__ __launch_bounds__(256, 8) void vq_phaseB_kernel(
    const float* __restrict__ zpack, const short* __restrict__ ebf,
    const float* __restrict__ se, const unsigned int* __restrict__ smin,
    const float* __restrict__ embed, unsigned long long* __restrict__ keys,
    int vchunk, int nmax)
{
  __shared__ __align__(16) short elds[WIN * 40];
  __shared__ float selds[WIN];
  __shared__ unsigned long long clist[CAP];
  __shared__ int ccnt;

  const int tid = threadIdx.x;
  const int lane = tid & 63, wave = tid >> 6;
  const int col = lane & 15, quad = lane >> 4;
  const int nw = blockIdx.x * 256 + wave * 64;
  const int vbase = blockIdx.y * vchunk;
  const float MARGIN = 1.0f;   // on s-scale; bf16 |err| << 0.5 here

  if (tid == 0) ccnt = 0;
  __syncthreads();

  bf16x8 af[4];
#pragma unroll
  for (int f = 0; f < 4; ++f) {
    const float* zb = zpack + (nw + f * 16 + col);
#pragma unroll
    for (int j = 0; j < 8; ++j)
      af[f][j] = f2bf(-zb[(size_t)(quad * 8 + j) * ZS]);
  }
  float thr[4][4];
#pragma unroll
  for (int f = 0; f < 4; ++f)
#pragma unroll
    for (int r = 0; r < 4; ++r)
      thr[f][r] = decf(smin[nw + f * 16 + quad * 4 + r]) + MARGIN;

  for (int w0 = 0; w0 < vchunk; w0 += WIN) {
    __syncthreads();
    {
      int row = tid >> 1, half = tid & 1;       // full-row staging (see A)
      const bf16x8* src = (const bf16x8*)(ebf + (size_t)(vbase + w0 + row) * 32);
      bf16x8* dst = (bf16x8*)(elds + row * 40);
      dst[half * 2]     = src[half * 2];
      dst[half * 2 + 1] = src[half * 2 + 1];
      if (tid < WIN) selds[tid] = 0.5f * se[vbase + w0 + tid];
    }
    __syncthreads();
    for (int vv = 0; vv < WIN; vv += 16) {
      bf16x8 bf = *(const bf16x8*)(elds + (vv + col) * 40 + quad * 8);
      float sevh = selds[vv + col];
      f32x4 cin = {sevh, sevh, sevh, sevh};
      f32x4 dd[4];
      float hm = 3.4e38f;
#pragma unroll
      for (int f = 0; f < 4; ++f) {
        dd[f] = __builtin_amdgcn_mfma_f32_16x16x32_bf16(af[f], bf, cin, 0, 0, 0);
#pragma unroll
        for (int r = 0; r < 4; ++r) hm = fminf(hm, dd[f][r] - thr[f][r]);
      }
      if (hm <= 0.f) {       // some lane has a candidate in this 16-code slab
#pragma unroll
        for (int f = 0; f < 4; ++f) {
#pragma unroll
          for (int r = 0; r < 4; ++r) {
            if (dd[f][r] <= thr[f][r]) {
              int n = nw + f * 16 + quad * 4 + r;
              int v = vbase + w0 + vv + col;
              int slot = atomicAdd(&ccnt, 1);   // LDS atomic: fast
              if (slot < CAP) {
                clist[slot] =
                    ((unsigned long long)(unsigned)n << 32) | (unsigned)v;
              } else {
                // overflow fallback: exact inline (ascending-c fp order)
                const float* zp = zpack + n;
                const float* ep = embed + (size_t)v * 32;
                float dot = 0.f, sz = 0.f;
#pragma unroll 1
                for (int i = 0; i < 32; ++i) {
                  float zc = zp[(size_t)i * ZS];
                  dot = fmaf(zc, ep[i], dot);
                  sz  = fmaf(zc, zc, sz);
                }
                float d = fmaf(-2.0f, dot, sz) + se[v];
                unsigned long long key =
                    ((unsigned long long)encf(d) << 32) | (unsigned)v;
                atomicMin(&keys[n], key);
              }
            }
          }
        }
      }
    }
  }

  // batch exact-fp32 rescue (dot and sz both accumulate ascending c --
  // identical fp order to r1-r14's passing formula)
  __syncthreads();
  int tot = min(ccnt, CAP);
  for (int j = tid; j < tot; j += 256) {
    unsigned long long cv = clist[j];
    int n = min((int)(cv >> 32), nmax - 1);
    int v = min((int)(cv & 0xffffffffull), V_ - 1);
    const float* zp = zpack + n;
    const float* ep = embed + (size_t)v * 32;
    float dot = 0.f, sz = 0.f;
#pragma unroll
    for (int i = 0; i < 32; ++i) {
      float zc = zp[(size_t)i * ZS];
      dot = fmaf(zc, ep[i], dot);
      sz  = fmaf(zc, zc, sz);
    }
    float d = fmaf(-2.0f, dot, sz) + se[v];
    unsigned long long key =
        ((unsigned long long)encf(d) << 32) | (unsigned)v;
    atomicMin(&keys[n], key);
  }
}

// ---- upsample + f_rest update + loss + idx out + next-scale prep ----
// block = one (b,c) plane; blockIdx.x = b*32+c; tid = o*16+p
// (f_hat no longer materialized -- final_add reconstructs it)
__global__ __launch_bounds__(256) void up_update_kernel(
    const float* __restrict__ embed, const unsigned long long* __restrict__ keys,
    const float* __restrict__ tbl, float* __restrict__ f_rest, int pn,
    float* __restrict__ zpack_next, unsigned long long* __restrict__ keys_nb,
    unsigned int* __restrict__ smin_nb, int pn_next, int n_next,
    float* __restrict__ idx_out, float* __restrict__ loss_slot)
{
  __shared__ float sm[256];
  __shared__ float sm_e[64];
  const int tid = threadIdx.x;
  const int t = blockIdx.x * 256 + tid;
  const int p = tid & 15, o = tid >> 4;
  const int c = blockIdx.x & 31, b = blockIdx.x >> 5;
  const int pn2 = pn * pn;

  float pre = f_rest[t];
  sm[tid] = pre;
  if (tid < pn2) {
    int idx = keyidx(keys[b * pn2 + tid]);
    if (c == 0) idx_out[b * pn2 + tid] = (float)idx;
    sm_e[tid] = embed[(size_t)idx * 32 + c];
  }
  __syncthreads();

  // loss partial: recompute zavg from pre-update plane (== zpack exactly)
  float lsum = 0.f;
  if (tid < pn2) {
    int k = 16 / pn;
    int ph = tid / pn, pw = tid - ph * pn;
    float s = 0.f;
    for (int i = 0; i < k; ++i)
      for (int j = 0; j < k; ++j)
        s += sm[(ph * k + i) * 16 + (pw * k + j)];
    float zavg = s * (1.0f / (k * k));
    float d = sm_e[tid] - zavg;
    lsum = d * d;
  }
#pragma unroll
  for (int off = 32; off > 0; off >>= 1) lsum += __shfl_down(lsum, off, 64);
  if ((tid & 63) == 0)
    atomicAdd(loss_slot + ((blockIdx.x & 127) << 4), lsum);

  // bicubic upsample (ref: h-einsum first, then w)
  const float* Wo = tbl + o * 8;
  const float* Wp = tbl + p * 8;
  float acc = 0.f;
  for (int w = 0; w < pn; ++w) {
    float inner = 0.f;
    for (int h = 0; h < pn; ++h)
      inner = fmaf(Wo[h], sm_e[h * pn + w], inner);
    acc = fmaf(Wp[w], inner, acc);
  }
  float nr = pre - acc;
  f_rest[t] = nr;

  __syncthreads();
  sm[tid] = nr;
  __syncthreads();
  const int pnn2 = pn_next * pn_next;
  if (tid < pnn2) {
    int ph = tid / pn_next, pw = tid - ph * pn_next;
    int k = 16 / pn_next;
    float s = 0.f;
    for (int i = 0; i < k; ++i)
      for (int j = 0; j < k; ++j)
        s += sm[(ph * k + i) * 16 + (pw * k + j)];
    // col-major, block-contiguous: full cachelines per block at pn_next>=8
    zpack_next[c * ZS + b * pnn2 + tid] = s * (1.0f / (k * k));
  }
  if (t < n_next) {                // reset ping-pong buffers for next scale
    keys_nb[t] = ~0ull;
    smin_nb[t] = 0xFFFFFFFFu;
  }
}

// -- final scale (pn=16): out = (z - f_rest) + embed[idx], idx out, loss --
__global__ __launch_bounds__(256) void final_add_kernel(
    const float* __restrict__ z, const float* __restrict__ f_rest,
    const float* __restrict__ embed, const unsigned long long* __restrict__ keys,
    float* __restrict__ f_hat, const float* __restrict__ zpack,
    float* __restrict__ idx_out, float* __restrict__ loss_slot)
{
  const int tid = threadIdx.x;
  const int t = blockIdx.x * 256 + tid;
  const int c = blockIdx.x & 31, b = blockIdx.x >> 5;
  const int n = b * 256 + tid;
  int idx = keyidx(keys[n]);
  if (c == 0) idx_out[n] = (float)idx;
  float e = embed[(size_t)idx * 32 + c];
  f_hat[t] = (z[t] - f_rest[t]) + e;   // f_hat = sum of zq (err ~1e-6)
  float d = e - zpack[c * ZS + n];     // col-major: coalesced across tid
  float lsum = d * d;
#pragma unroll
  for (int off = 32; off > 0; off >>= 1) lsum += __shfl_down(lsum, off, 64);
  if ((tid & 63) == 0)
    atomicAdd(loss_slot + ((blockIdx.x & 127) << 4), lsum);
}

// ------------- final loss reduce: 5 scales x 128 padded slots -------------
__global__ __launch_bounds__(128) void loss_final_kernel(
    const float* __restrict__ loss_slots, float* __restrict__ out_loss)
{
  __shared__ float lred[2];
  const int tid = threadIdx.x;   // 128 threads = 2 waves
  const float numel[5] = {8192.f, 32768.f, 131072.f, 524288.f, 2097152.f};
  float tot = 0.f;
  for (int s = 0; s < 5; ++s) {
    float x = loss_slots[s * 2048 + tid * 16];
#pragma unroll
    for (int off = 32; off > 0; off >>= 1) x += __shfl_down(x, off, 64);
    if ((tid & 63) == 0) lred[tid >> 6] = x;
    __syncthreads();
    if (tid == 0) {
      float m = (lred[0] + lred[1]) / numel[s];
      tot += 0.25f * m + m;        // beta*mean + mean
    }
    __syncthreads();
  }
  if (tid == 0) out_loss[0] = tot / 5.f;
}

// =========================== host launcher ===========================
extern "C" void kernel_launch(void* const* d_in, const int* in_sizes, int n_in,
                              void* d_out, int out_size, void* d_ws, size_t ws_size,
                              hipStream_t stream)
{
  const float* z     = (const float*)d_in[0];
  const float* embed = (const float*)d_in[1];
  float* out = (float*)d_out;
  float* ws  = (float*)d_ws;

  // ws layout (float slots), total 4520448 floats ~= 17.24 MiB
  float* f_rest = ws;                                    // 2097152
  float* zpack  = ws + 2097152;                          // 32*65536 col-major
  short* ebf    = (short*)(ws + 4194304);                // 131072 shorts
  float* se     = ws + 4259840;                          // 4096
  unsigned int* smin0 = (unsigned int*)(ws + 4263936);   // 65536 u32
  unsigned int* smin1 = (unsigned int*)(ws + 4329472);   // 16384 u32
  unsigned long long* keys0 = (unsigned long long*)(ws + 4345856); // 65536 u64
  unsigned long long* keys1 = (unsigned long long*)(ws + 4476928); // 16384 u64
  float* loss_slots = ws + 4509696;                      // 5*128*16 = 10240
  float* tables     = ws + 4519936;                      // 512

  unsigned long long* keysb[2] = {keys0, keys1};
  unsigned int*       sminb[2] = {smin0, smin1};

  setup_kernel<<<NTOT / 256, 256, 0, stream>>>(z, embed, f_rest, zpack,
                                               ebf, se, tables, loss_slots,
                                               keys0, smin0);

  const int PN[5]  = {1, 2, 4, 8, 16};
  const int NVC[5] = {32, 32, 32, 32, 32};  // vchunk = 128 = WIN everywhere
  int idx_off = NTOT;
  for (int i = 0; i < 5; ++i) {
    int pn = PN[i];
    int N  = B_ * pn * pn;
    int vchunk = V_ / NVC[i];
    unsigned long long* kb = keysb[i & 1];
    unsigned int*       sb = sminb[i & 1];
    dim3 g(N / 256, NVC[i]);
    vq_phaseA_kernel<<<g, 256, 0, stream>>>(zpack, ebf, se, sb, vchunk);
    vq_phaseB_kernel<<<g, 256, 0, stream>>>(zpack, ebf, se, sb, embed, kb,
                                            vchunk, N);
    if (i < 4) {
      int pnn = PN[i + 1];
      up_update_kernel<<<NTOT / 256, 256, 0, stream>>>(
          embed, kb, tables + i * 128, f_rest, pn,
          zpack, keysb[(i + 1) & 1], sminb[(i + 1) & 1],
          pnn, B_ * pnn * pnn, out + idx_off, loss_slots + i * 2048);
    } else {
      final_add_kernel<<<NTOT / 256, 256, 0, stream>>>(
          z, f_rest, embed, kb, out, zpack, out + idx_off,
          loss_slots + 4 * 2048);
    }
    idx_off += N;
  }
  loss_final_kernel<<<1, 128, 0, stream>>>(loss_slots, out + 2184448);
}

// Round 16
// 380.417 us; speedup vs baseline: 1.7790x; 1.7790x over previous
//
#include <hip/hip_runtime.h>
#include <hip/hip_bf16.h>
#include <cstdint>
#include <cstddef>

// MultiScaleQuantizer: z (256,32,16,16) fp32, embed (4096,32) fp32.
// Outputs concat (fp32): f_hat (2097152), idx@pn=1..16 (87296), loss (1).
//
// r16 = r14 base (r15's forced __launch_bounds__(256,8) caused VGPR spilling:
// VGPR 68->32 with 626MB scratch WRITE_SIZE, 78->185us) with register
// pressure reduced STRUCTURALLY: each wave owns 32 points (2 frags, af[2]/
// thr[2][4]/dd[2] ~= -24 live VGPRs) -> under the 64-reg 8-waves/SIMD cliff
// without spills. grid.x = N/128 (2x waves, same total work).

#define B_   256
#define V_   4096
#define NTOT 2097152   // 256*32*16*16
#define WIN  128       // codebook window staged in LDS
#define CAP  512       // candidate list capacity per block
#define ZS   65536     // zpack column stride (max N)

using bf16x8 = __attribute__((ext_vector_type(8))) short;
using f32x4  = __attribute__((ext_vector_type(4))) float;

__device__ inline short f2bf(float f) {
  __hip_bfloat16 h = __float2bfloat16(f);
  return *reinterpret_cast<short*>(&h);
}
__device__ inline unsigned encf(float f) {        // monotone fp32 -> u32
  unsigned u = __float_as_uint(f);
  return (u & 0x80000000u) ? ~u : (u | 0x80000000u);
}
__device__ inline float decf(unsigned u) {
  unsigned b = (u & 0x80000000u) ? (u ^ 0x80000000u) : ~u;
  return __uint_as_float(b);
}
__device__ inline int keyidx(unsigned long long k) {  // decode + clamp (safety)
  int i = (int)(unsigned)(k & 0xffffffffull);
  return min(max(i, 0), V_ - 1);
}

// ---- setup: f_rest=z, zpack@pn1 (col-major), ebf, se, tables, inits ----
// block = one (b,c) plane; blockIdx.x = b*32+c
__global__ __launch_bounds__(256) void setup_kernel(
    const float* __restrict__ z, const float* __restrict__ embed,
    float* __restrict__ f_rest, float* __restrict__ zpack,
    short* __restrict__ ebf, float* __restrict__ se,
    float* __restrict__ tables, float* __restrict__ loss_slots,
    unsigned long long* __restrict__ keys0, unsigned int* __restrict__ smin0)
{
  const int tid = threadIdx.x;
  const int t = blockIdx.x * 256 + tid;
  float v = z[t];
  f_rest[t] = v;

  __shared__ float sm[256];
  sm[tid] = v;
  __syncthreads();
  if (tid == 0) {
    float s = 0.f;
    for (int i = 0; i < 256; ++i) s += sm[i];   // ref's linear i,j order
    int c = blockIdx.x & 31, b = blockIdx.x >> 5;
    zpack[c * ZS + b] = s * (1.0f / 256.0f);    // column-major
  }

  if (blockIdx.x < 16) {                        // se + ebf: 16*256 codes
    int code = blockIdx.x * 256 + tid;
    float s = 0.f;
#pragma unroll
    for (int c = 0; c < 32; ++c) {
      float e = embed[(size_t)code * 32 + c];
      ebf[(size_t)code * 32 + c] = f2bf(e);
      s += e * e;                                // sequential like ref
    }
    se[code] = s;
  } else if (blockIdx.x == 16) {
    if (tid < 64) {
      int pn_i = tid >> 4;          // 0..3 -> pn = 1,2,4,8
      int o    = tid & 15;
      int pn   = 1 << pn_i;
      double scale = (double)pn / 16.0;
      double x  = (o + 0.5) * scale - 0.5;
      double x0 = floor(x);
      double tf = x - x0;
      float row[8];
#pragma unroll
      for (int h = 0; h < 8; ++h) row[h] = 0.f;
      const double A = -0.75;
#pragma unroll
      for (int off = -1; off <= 2; ++off) {
        double s = fabs(tf - (double)off);
        double cub;
        if (s <= 1.0)      cub = ((A + 2.0) * s - (A + 3.0)) * s * s + 1.0;
        else if (s < 2.0)  cub = (((s - 5.0) * s + 8.0) * s - 4.0) * A;
        else               cub = 0.0;
        int idx = (int)x0 + off;
        idx = min(max(idx, 0), pn - 1);
        row[idx] = (float)((double)row[idx] + cub);  // numpy f32 += f64
      }
#pragma unroll
      for (int h = 0; h < 8; ++h) tables[pn_i * 128 + o * 8 + h] = row[h];
    }
  } else if (blockIdx.x == 17) {
    keys0[tid] = ~0ull;                          // pn=1: N=256
    smin0[tid] = 0xFFFFFFFFu;
  } else if (blockIdx.x >= 20 && blockIdx.x < 60) {
    loss_slots[(blockIdx.x - 20) * 256 + tid] = 0.f;   // 40*256 = 10240 zeros
  }
}

// ---------------- phase A: MFMA scan -> per-point min of s=se/2-dot ----------
// block 256 = 4 waves x 32 points (2 frags/wave); grid.x = N/128,
// grid.y = v-chunks
__global__ __launch_bounds__(256) void vq_phaseA_kernel(
    const float* __restrict__ zpack, const short* __restrict__ ebf,
    const float* __restrict__ se, unsigned int* __restrict__ smin,
    int vchunk)
{
  __shared__ __align__(16) short elds[WIN * 40]; // padded stride 80B rows
  __shared__ float selds[WIN];

  const int tid = threadIdx.x;
  const int lane = tid & 63, wave = tid >> 6;
  const int col = lane & 15, quad = lane >> 4;
  const int nw = blockIdx.x * 128 + wave * 32;
  const int vbase = blockIdx.y * vchunk;

  // A-frags: 2 frags x 16 points; lane holds A[m=col][k=quad*8+j], A = -z bf16
  bf16x8 af[2];
#pragma unroll
  for (int f = 0; f < 2; ++f) {
    const float* zb = zpack + (nw + f * 16 + col);
#pragma unroll
    for (int j = 0; j < 8; ++j)
      af[f][j] = f2bf(-zb[(size_t)(quad * 8 + j) * ZS]);
  }
  float mn[2][4];
#pragma unroll
  for (int f = 0; f < 2; ++f)
#pragma unroll
    for (int r = 0; r < 4; ++r) mn[f][r] = 3.4e38f;

  for (int w0 = 0; w0 < vchunk; w0 += WIN) {
    __syncthreads();
    {
      // 128 rows x 2 threads; each thread stores 2 bf16x8 = full 32-short row
      int row = tid >> 1, half = tid & 1;
      const bf16x8* src = (const bf16x8*)(ebf + (size_t)(vbase + w0 + row) * 32);
      bf16x8* dst = (bf16x8*)(elds + row * 40);
      dst[half * 2]     = src[half * 2];
      dst[half * 2 + 1] = src[half * 2 + 1];
      if (tid < WIN) selds[tid] = 0.5f * se[vbase + w0 + tid];  // *0.5 exact
    }
    __syncthreads();
    for (int vv = 0; vv < WIN; vv += 16) {
      bf16x8 bf = *(const bf16x8*)(elds + (vv + col) * 40 + quad * 8);
      float sevh = selds[vv + col];
      f32x4 cin = {sevh, sevh, sevh, sevh};       // D = se/2 + (-z)*e
#pragma unroll
      for (int f = 0; f < 2; ++f) {
        f32x4 d = __builtin_amdgcn_mfma_f32_16x16x32_bf16(af[f], bf, cin, 0, 0, 0);
#pragma unroll
        for (int r = 0; r < 4; ++r) mn[f][r] = fminf(mn[f][r], d[r]);
      }
    }
  }
  // cross-col min via shuffle butterfly
#pragma unroll
  for (int f = 0; f < 2; ++f)
#pragma unroll
    for (int r = 0; r < 4; ++r) {
      float m = mn[f][r];
      m = fminf(m, __shfl_xor(m, 1, 64));
      m = fminf(m, __shfl_xor(m, 2, 64));
      m = fminf(m, __shfl_xor(m, 4, 64));
      m = fminf(m, __shfl_xor(m, 8, 64));
      mn[f][r] = m;
    }
  if (col == 0) {
#pragma unroll
    for (int f = 0; f < 2; ++f)
#pragma unroll
      for (int r = 0; r < 4; ++r)
        atomicMin(&smin[nw + f * 16 + quad * 4 + r], encf(mn[f][r]));
  }
}

// -------- phase B: MFMA re-scan; candidates -> LDS list -> batch rescue -----
__global__ __launch_bounds__(256) void vq_phaseB_kernel(
    const float* __restrict__ zpack, const short* __restrict__ ebf,
    const float* __restrict__ se, const unsigned int* __restrict__ smin,
    const float* __restrict__ embed, unsigned long long* __restrict__ keys,
    int vchunk, int nmax)
{
  __shared__ __align__(16) short elds[WIN * 40];
  __shared__ float selds[WIN];
  __shared__ unsigned long long clist[CAP];
  __shared__ int ccnt;

  const int tid = threadIdx.x;
  const int lane = tid & 63, wave = tid >> 6;
  const int col = lane & 15, quad = lane >> 4;
  const int nw = blockIdx.x * 128 + wave * 32;
  const int vbase = blockIdx.y * vchunk;
  const float MARGIN = 1.0f;   // on s-scale; bf16 |err| << 0.5 here

  if (tid == 0) ccnt = 0;
  __syncthreads();

  bf16x8 af[2];
#pragma unroll
  for (int f = 0; f < 2; ++f) {
    const float* zb = zpack + (nw + f * 16 + col);
#pragma unroll
    for (int j = 0; j < 8; ++j)
      af[f][j] = f2bf(-zb[(size_t)(quad * 8 + j) * ZS]);
  }
  float thr[2][4];
#pragma unroll
  for (int f = 0; f < 2; ++f)
#pragma unroll
    for (int r = 0; r < 4; ++r)
      thr[f][r] = decf(smin[nw + f * 16 + quad * 4 + r]) + MARGIN;

  for (int w0 = 0; w0 < vchunk; w0 += WIN) {
    __syncthreads();
    {
      int row = tid >> 1, half = tid & 1;       // full-row staging (see A)
      const bf16x8* src = (const bf16x8*)(ebf + (size_t)(vbase + w0 + row) * 32);
      bf16x8* dst = (bf16x8*)(elds + row * 40);
      dst[half * 2]     = src[half * 2];
      dst[half * 2 + 1] = src[half * 2 + 1];
      if (tid < WIN) selds[tid] = 0.5f * se[vbase + w0 + tid];
    }
    __syncthreads();
    for (int vv = 0; vv < WIN; vv += 16) {
      bf16x8 bf = *(const bf16x8*)(elds + (vv + col) * 40 + quad * 8);
      float sevh = selds[vv + col];
      f32x4 cin = {sevh, sevh, sevh, sevh};
      f32x4 dd[2];
      float hm = 3.4e38f;
#pragma unroll
      for (int f = 0; f < 2; ++f) {
        dd[f] = __builtin_amdgcn_mfma_f32_16x16x32_bf16(af[f], bf, cin, 0, 0, 0);
#pragma unroll
        for (int r = 0; r < 4; ++r) hm = fminf(hm, dd[f][r] - thr[f][r]);
      }
      if (hm <= 0.f) {       // some lane has a candidate in this 16-code slab
#pragma unroll
        for (int f = 0; f < 2; ++f) {
#pragma unroll
          for (int r = 0; r < 4; ++r) {
            if (dd[f][r] <= thr[f][r]) {
              int n = nw + f * 16 + quad * 4 + r;
              int v = vbase + w0 + vv + col;
              int slot = atomicAdd(&ccnt, 1);   // LDS atomic: fast
              if (slot < CAP) {
                clist[slot] =
                    ((unsigned long long)(unsigned)n << 32) | (unsigned)v;
              } else {
                // overflow fallback: exact inline (ascending-c fp order)
                const float* zp = zpack + n;
                const float* ep = embed + (size_t)v * 32;
                float dot = 0.f, sz = 0.f;
#pragma unroll 1
                for (int i = 0; i < 32; ++i) {
                  float zc = zp[(size_t)i * ZS];
                  dot = fmaf(zc, ep[i], dot);
                  sz  = fmaf(zc, zc, sz);
                }
                float d = fmaf(-2.0f, dot, sz) + se[v];
                unsigned long long key =
                    ((unsigned long long)encf(d) << 32) | (unsigned)v;
                atomicMin(&keys[n], key);
              }
            }
          }
        }
      }
    }
  }

  // batch exact-fp32 rescue (dot and sz both accumulate ascending c --
  // identical fp order to r1-r14's passing formula)
  __syncthreads();
  int tot = min(ccnt, CAP);
  for (int j = tid; j < tot; j += 256) {
    unsigned long long cv = clist[j];
    int n = min((int)(cv >> 32), nmax - 1);
    int v = min((int)(cv & 0xffffffffull), V_ - 1);
    const float* zp = zpack + n;
    const float* ep = embed + (size_t)v * 32;
    float dot = 0.f, sz = 0.f;
#pragma unroll
    for (int i = 0; i < 32; ++i) {
      float zc = zp[(size_t)i * ZS];
      dot = fmaf(zc, ep[i], dot);
      sz  = fmaf(zc, zc, sz);
    }
    float d = fmaf(-2.0f, dot, sz) + se[v];
    unsigned long long key =
        ((unsigned long long)encf(d) << 32) | (unsigned)v;
    atomicMin(&keys[n], key);
  }
}

// ---- upsample + f_rest update + loss + idx out + next-scale prep ----
// block = one (b,c) plane; blockIdx.x = b*32+c; tid = o*16+p
// (f_hat no longer materialized -- final_add reconstructs it)
__global__ __launch_bounds__(256) void up_update_kernel(
    const float* __restrict__ embed, const unsigned long long* __restrict__ keys,
    const float* __restrict__ tbl, float* __restrict__ f_rest, int pn,
    float* __restrict__ zpack_next, unsigned long long* __restrict__ keys_nb,
    unsigned int* __restrict__ smin_nb, int pn_next, int n_next,
    float* __restrict__ idx_out, float* __restrict__ loss_slot)
{
  __shared__ float sm[256];
  __shared__ float sm_e[64];
  const int tid = threadIdx.x;
  const int t = blockIdx.x * 256 + tid;
  const int p = tid & 15, o = tid >> 4;
  const int c = blockIdx.x & 31, b = blockIdx.x >> 5;
  const int pn2 = pn * pn;

  float pre = f_rest[t];
  sm[tid] = pre;
  if (tid < pn2) {
    int idx = keyidx(keys[b * pn2 + tid]);
    if (c == 0) idx_out[b * pn2 + tid] = (float)idx;
    sm_e[tid] = embed[(size_t)idx * 32 + c];
  }
  __syncthreads();

  // loss partial: recompute zavg from pre-update plane (== zpack exactly)
  float lsum = 0.f;
  if (tid < pn2) {
    int k = 16 / pn;
    int ph = tid / pn, pw = tid - ph * pn;
    float s = 0.f;
    for (int i = 0; i < k; ++i)
      for (int j = 0; j < k; ++j)
        s += sm[(ph * k + i) * 16 + (pw * k + j)];
    float zavg = s * (1.0f / (k * k));
    float d = sm_e[tid] - zavg;
    lsum = d * d;
  }
#pragma unroll
  for (int off = 32; off > 0; off >>= 1) lsum += __shfl_down(lsum, off, 64);
  if ((tid & 63) == 0)
    atomicAdd(loss_slot + ((blockIdx.x & 127) << 4), lsum);

  // bicubic upsample (ref: h-einsum first, then w)
  const float* Wo = tbl + o * 8;
  const float* Wp = tbl + p * 8;
  float acc = 0.f;
  for (int w = 0; w < pn; ++w) {
    float inner = 0.f;
    for (int h = 0; h < pn; ++h)
      inner = fmaf(Wo[h], sm_e[h * pn + w], inner);
    acc = fmaf(Wp[w], inner, acc);
  }
  float nr = pre - acc;
  f_rest[t] = nr;

  __syncthreads();
  sm[tid] = nr;
  __syncthreads();
  const int pnn2 = pn_next * pn_next;
  if (tid < pnn2) {
    int ph = tid / pn_next, pw = tid - ph * pn_next;
    int k = 16 / pn_next;
    float s = 0.f;
    for (int i = 0; i < k; ++i)
      for (int j = 0; j < k; ++j)
        s += sm[(ph * k + i) * 16 + (pw * k + j)];
    // col-major, block-contiguous: full cachelines per block at pn_next>=8
    zpack_next[c * ZS + b * pnn2 + tid] = s * (1.0f / (k * k));
  }
  if (t < n_next) {                // reset ping-pong buffers for next scale
    keys_nb[t] = ~0ull;
    smin_nb[t] = 0xFFFFFFFFu;
  }
}

// -- final scale (pn=16): out = (z - f_rest) + embed[idx], idx out, loss --
__global__ __launch_bounds__(256) void final_add_kernel(
    const float* __restrict__ z, const float* __restrict__ f_rest,
    const float* __restrict__ embed, const unsigned long long* __restrict__ keys,
    float* __restrict__ f_hat, const float* __restrict__ zpack,
    float* __restrict__ idx_out, float* __restrict__ loss_slot)
{
  const int tid = threadIdx.x;
  const int t = blockIdx.x * 256 + tid;
  const int c = blockIdx.x & 31, b = blockIdx.x >> 5;
  const int n = b * 256 + tid;
  int idx = keyidx(keys[n]);
  if (c == 0) idx_out[n] = (float)idx;
  float e = embed[(size_t)idx * 32 + c];
  f_hat[t] = (z[t] - f_rest[t]) + e;   // f_hat = sum of zq (err ~1e-6)
  float d = e - zpack[c * ZS + n];     // col-major: coalesced across tid
  float lsum = d * d;
#pragma unroll
  for (int off = 32; off > 0; off >>= 1) lsum += __shfl_down(lsum, off, 64);
  if ((tid & 63) == 0)
    atomicAdd(loss_slot + ((blockIdx.x & 127) << 4), lsum);
}

// ------------- final loss reduce: 5 scales x 128 padded slots -------------
__global__ __launch_bounds__(128) void loss_final_kernel(
    const float* __restrict__ loss_slots, float* __restrict__ out_loss)
{
  __shared__ float lred[2];
  const int tid = threadIdx.x;   // 128 threads = 2 waves
  const float numel[5] = {8192.f, 32768.f, 131072.f, 524288.f, 2097152.f};
  float tot = 0.f;
  for (int s = 0; s < 5; ++s) {
    float x = loss_slots[s * 2048 + tid * 16];
#pragma unroll
    for (int off = 32; off > 0; off >>= 1) x += __shfl_down(x, off, 64);
    if ((tid & 63) == 0) lred[tid >> 6] = x;
    __syncthreads();
    if (tid == 0) {
      float m = (lred[0] + lred[1]) / numel[s];
      tot += 0.25f * m + m;        // beta*mean + mean
    }
    __syncthreads();
  }
  if (tid == 0) out_loss[0] = tot / 5.f;
}

// =========================== host launcher ===========================
extern "C" void kernel_launch(void* const* d_in, const int* in_sizes, int n_in,
                              void* d_out, int out_size, void* d_ws, size_t ws_size,
                              hipStream_t stream)
{
  const float* z     = (const float*)d_in[0];
  const float* embed = (const float*)d_in[1];
  float* out = (float*)d_out;
  float* ws  = (float*)d_ws;

  // ws layout (float slots), total 4520448 floats ~= 17.24 MiB
  float* f_rest = ws;                                    // 2097152
  float* zpack  = ws + 2097152;                          // 32*65536 col-major
  short* ebf    = (short*)(ws + 4194304);                // 131072 shorts
  float* se     = ws + 4259840;                          // 4096
  unsigned int* smin0 = (unsigned int*)(ws + 4263936);   // 65536 u32
  unsigned int* smin1 = (unsigned int*)(ws + 4329472);   // 16384 u32
  unsigned long long* keys0 = (unsigned long long*)(ws + 4345856); // 65536 u64
  unsigned long long* keys1 = (unsigned long long*)(ws + 4476928); // 16384 u64
  float* loss_slots = ws + 4509696;                      // 5*128*16 = 10240
  float* tables     = ws + 4519936;                      // 512

  unsigned long long* keysb[2] = {keys0, keys1};
  unsigned int*       sminb[2] = {smin0, smin1};

  setup_kernel<<<NTOT / 256, 256, 0, stream>>>(z, embed, f_rest, zpack,
                                               ebf, se, tables, loss_slots,
                                               keys0, smin0);

  const int PN[5]  = {1, 2, 4, 8, 16};
  const int NVC[5] = {32, 32, 32, 16, 16};  // v-chunks; vchunk multiple of WIN
  int idx_off = NTOT;
  for (int i = 0; i < 5; ++i) {
    int pn = PN[i];
    int N  = B_ * pn * pn;
    int vchunk = V_ / NVC[i];
    unsigned long long* kb = keysb[i & 1];
    unsigned int*       sb = sminb[i & 1];
    dim3 g(N / 128, NVC[i]);                  // 2-frag waves: 128 points/block
    vq_phaseA_kernel<<<g, 256, 0, stream>>>(zpack, ebf, se, sb, vchunk);
    vq_phaseB_kernel<<<g, 256, 0, stream>>>(zpack, ebf, se, sb, embed, kb,
                                            vchunk, N);
    if (i < 4) {
      int pnn = PN[i + 1];
      up_update_kernel<<<NTOT / 256, 256, 0, stream>>>(
          embed, kb, tables + i * 128, f_rest, pn,
          zpack, keysb[(i + 1) & 1], sminb[(i + 1) & 1],
          pnn, B_ * pnn * pnn, out + idx_off, loss_slots + i * 2048);
    } else {
      final_add_kernel<<<NTOT / 256, 256, 0, stream>>>(
          z, f_rest, embed, kb, out, zpack, out + idx_off,
          loss_slots + 4 * 2048);
    }
    idx_off += N;
  }
  loss_final_kernel<<<1, 128, 0, stream>>>(loss_slots, out + 2184448);
}